// Round 1
// baseline (726.893 us; speedup 1.0000x reference)
//
#include <hip/hip_runtime.h>

// Problem: 2-layer LSTM (PyTorch convention), B=64, T=1024, D=512, H=32, fp32.
// Phase 1: xg0[m][g] = b0[g] + sum_d x[m][d]*Wih0[g][d], m = b*T + t  (GEMM, parallel)
// Phase 2: fused sequential scan over T, one block per batch element.

#define TT 1024
#define BB 64
#define DD 512
#define HH 32
#define GG 128  // 4*H

__device__ __forceinline__ float fast_rcp(float x) { return __builtin_amdgcn_rcpf(x); }

__device__ __forceinline__ float activate(float s, bool ist) {
  // sigmoid(s) or tanh(s) = 2*sigmoid(2s)-1, branchless
  float z = ist ? s + s : s;
  float r = fast_rcp(1.f + __expf(-z));
  return ist ? fmaf(2.f, r, -1.f) : r;
}

__device__ __forceinline__ float fast_tanh(float x) {
  float r = fast_rcp(1.f + __expf(-2.f * x));
  return fmaf(2.f, r, -1.f);
}

// ---------------- Phase 1: xg GEMM ----------------
// grid 1024 blocks, 256 threads. Block tile: 64 M x 128 N, K-step 16.
__global__ __launch_bounds__(256) void xg_gemm(const float* __restrict__ x,
                                               const float* __restrict__ W,
                                               const float* __restrict__ bih,
                                               const float* __restrict__ bhh,
                                               float* __restrict__ outp) {
  __shared__ float xs[16][68];   // [k][m], pad 68 -> 272B row (16B aligned, conflict-safe)
  __shared__ float ws[16][128];  // [k][n]
  const int tid = threadIdx.x;
  const int m0 = blockIdx.x * 64;
  const int tr = tid >> 5;        // 0..7
  const int tc = tid & 31;        // 0..31
  const int tm = tr * 8;
  const int tn = tc * 4;
  // staging indices
  const int sxm = tid >> 2;            // 0..63
  const int sxk = (tid & 3) * 4;       // 0,4,8,12
  const int swg = tid >> 1;            // 0..127
  const int swk = (tid & 1) * 8;       // 0 or 8

  float acc[8][4];
#pragma unroll
  for (int i = 0; i < 8; ++i)
#pragma unroll
    for (int j = 0; j < 4; ++j) acc[i][j] = 0.f;

  for (int k0 = 0; k0 < DD; k0 += 16) {
    const float4 xv = *(const float4*)(x + (size_t)(m0 + sxm) * DD + k0 + sxk);
    xs[sxk + 0][sxm] = xv.x;
    xs[sxk + 1][sxm] = xv.y;
    xs[sxk + 2][sxm] = xv.z;
    xs[sxk + 3][sxm] = xv.w;
    const float4 wv0 = *(const float4*)(W + (size_t)swg * DD + k0 + swk);
    const float4 wv1 = *(const float4*)(W + (size_t)swg * DD + k0 + swk + 4);
    ws[swk + 0][swg] = wv0.x;
    ws[swk + 1][swg] = wv0.y;
    ws[swk + 2][swg] = wv0.z;
    ws[swk + 3][swg] = wv0.w;
    ws[swk + 4][swg] = wv1.x;
    ws[swk + 5][swg] = wv1.y;
    ws[swk + 6][swg] = wv1.z;
    ws[swk + 7][swg] = wv1.w;
    __syncthreads();
#pragma unroll
    for (int k = 0; k < 16; ++k) {
      const float4 a0 = *(const float4*)&xs[k][tm];
      const float4 a1 = *(const float4*)&xs[k][tm + 4];
      const float4 wv = *(const float4*)&ws[k][tn];
      const float xr[8] = {a0.x, a0.y, a0.z, a0.w, a1.x, a1.y, a1.z, a1.w};
      const float wr[4] = {wv.x, wv.y, wv.z, wv.w};
#pragma unroll
      for (int i = 0; i < 8; ++i)
#pragma unroll
        for (int j = 0; j < 4; ++j) acc[i][j] = fmaf(xr[i], wr[j], acc[i][j]);
    }
    __syncthreads();
  }
  const float4 bi = *(const float4*)(bih + tn);
  const float4 bh = *(const float4*)(bhh + tn);
  const float bs[4] = {bi.x + bh.x, bi.y + bh.y, bi.z + bh.z, bi.w + bh.w};
#pragma unroll
  for (int i = 0; i < 8; ++i) {
    float4 o;
    o.x = acc[i][0] + bs[0];
    o.y = acc[i][1] + bs[1];
    o.z = acc[i][2] + bs[2];
    o.w = acc[i][3] + bs[3];
    *(float4*)(outp + (size_t)(m0 + tm + i) * GG + tn) = o;
  }
}

// ---------------- Phase 2: fused 2-layer scan ----------------
// 64 blocks (one per batch), 256 threads.
// tid 0..127  : layer0 gate g=tid  (Whh0 row in regs)
// tid 128..255: layer1 gate g=tid-128 (Wih1 + Whh1 rows in regs)
// Pipelined: at iteration t, layer0 produces h0[t], layer1 produces h1[t-1].
__global__ __launch_bounds__(256) void lstm_scan(const float* __restrict__ xg,
                                                 const float* __restrict__ Whh0,
                                                 const float* __restrict__ Wih1,
                                                 const float* __restrict__ Whh1,
                                                 const float* __restrict__ bih1,
                                                 const float* __restrict__ bhh1,
                                                 float* __restrict__ out) {
  __shared__ alignas(16) float g0buf[GG];
  __shared__ alignas(16) float g1buf[GG];
  __shared__ alignas(16) float h0buf[HH];
  __shared__ alignas(16) float h1buf[HH];

  const int tid = threadIdx.x;
  const int b = blockIdx.x;
  const bool is_l0 = tid < GG;
  const int g = tid & (GG - 1);
  const bool ist = (g & 96) == 64;  // gate 'g' (tanh) is indices [64,96)

  // weights in registers
  float4 w0v[8];  // l0: Whh0[g][:], l1: Wih1[g][:]
  float4 w1v[8];  // l1: Whh1[g][:]
  float bias1 = 0.f;
  if (is_l0) {
    const float4* p = (const float4*)(Whh0 + (size_t)g * HH);
#pragma unroll
    for (int q = 0; q < 8; ++q) w0v[q] = p[q];
#pragma unroll
    for (int q = 0; q < 8; ++q) w1v[q] = make_float4(0.f, 0.f, 0.f, 0.f);
  } else {
    const float4* p0 = (const float4*)(Wih1 + (size_t)g * HH);
    const float4* p1 = (const float4*)(Whh1 + (size_t)g * HH);
#pragma unroll
    for (int q = 0; q < 8; ++q) w0v[q] = p0[q];
#pragma unroll
    for (int q = 0; q < 8; ++q) w1v[q] = p1[q];
    bias1 = bih1[g] + bhh1[g];
  }

  float c0 = 0.f;  // owned by tid<32  (c of layer0, j=tid)
  float c1 = 0.f;  // owned by tid in [128,160) (c of layer1, j=tid-128)

  if (tid < HH) h0buf[tid] = 0.f;
  if (tid >= GG && tid < GG + HH) h1buf[tid - GG] = 0.f;

  // prefetch ring (4-deep) of xg values for layer0 threads
  float xgbuf[4];
  if (is_l0) {
#pragma unroll
    for (int u = 0; u < 4; ++u) xgbuf[u] = xg[((size_t)b * TT + u) * GG + g];
  }
  __syncthreads();

  auto step = [&](bool do_l0, bool do_l1, int t, float xc) {
    // ---- phase A: gates ----
    if (is_l0) {
      if (do_l0) {
        const float4* hv = (const float4*)h0buf;
        float a0 = 0.f, a1 = 0.f, a2 = 0.f, a3 = 0.f;
#pragma unroll
        for (int q = 0; q < 8; ++q) {
          const float4 h4 = hv[q];
          const float4 w4 = w0v[q];
          a0 = fmaf(w4.x, h4.x, a0);
          a1 = fmaf(w4.y, h4.y, a1);
          a2 = fmaf(w4.z, h4.z, a2);
          a3 = fmaf(w4.w, h4.w, a3);
        }
        const float s = xc + ((a0 + a1) + (a2 + a3));
        g0buf[g] = activate(s, ist);
      }
    } else {
      if (do_l1) {
        const float4* h0v = (const float4*)h0buf;
        const float4* h1v = (const float4*)h1buf;
        float a0 = 0.f, a1 = 0.f, a2 = 0.f, a3 = 0.f;
        float d0 = 0.f, d1 = 0.f, d2 = 0.f, d3 = 0.f;
#pragma unroll
        for (int q = 0; q < 8; ++q) {
          const float4 h4 = h0v[q];
          const float4 w4 = w0v[q];
          a0 = fmaf(w4.x, h4.x, a0);
          a1 = fmaf(w4.y, h4.y, a1);
          a2 = fmaf(w4.z, h4.z, a2);
          a3 = fmaf(w4.w, h4.w, a3);
          const float4 k4 = h1v[q];
          const float4 u4 = w1v[q];
          d0 = fmaf(u4.x, k4.x, d0);
          d1 = fmaf(u4.y, k4.y, d1);
          d2 = fmaf(u4.z, k4.z, d2);
          d3 = fmaf(u4.w, k4.w, d3);
        }
        const float s = bias1 + ((a0 + a1) + (a2 + a3)) + ((d0 + d1) + (d2 + d3));
        g1buf[g] = activate(s, ist);
      }
    }
    __syncthreads();
    // ---- phase B: combine ----
    if (tid < HH) {
      if (do_l0) {
        const float gi = g0buf[tid];
        const float gf = g0buf[tid + 32];
        const float gg = g0buf[tid + 64];
        const float go = g0buf[tid + 96];
        c0 = fmaf(gf, c0, gi * gg);
        h0buf[tid] = go * fast_tanh(c0);
      }
    } else if (tid >= GG && tid < GG + HH) {
      if (do_l1) {
        const int j = tid - GG;
        const float gi = g1buf[j];
        const float gf = g1buf[j + 32];
        const float gg = g1buf[j + 64];
        const float go = g1buf[j + 96];
        c1 = fmaf(gf, c1, gi * gg);
        const float h = go * fast_tanh(c1);
        h1buf[j] = h;
        out[((size_t)b * TT + (t - 1)) * HH + j] = h;
      }
    }
    __syncthreads();
  };

  for (int tb = 0; tb < TT; tb += 4) {
#pragma unroll
    for (int u = 0; u < 4; ++u) {
      const int t = tb + u;
      const float xc = xgbuf[u];
      if (is_l0 && tb + 4 < TT) xgbuf[u] = xg[((size_t)b * TT + t + 4) * GG + g];
      step(true, t > 0, t, xc);
    }
  }
  // epilogue: final layer1 step (time T-1)
  step(false, true, TT, 0.f);
}

extern "C" void kernel_launch(void* const* d_in, const int* in_sizes, int n_in,
                              void* d_out, int out_size, void* d_ws, size_t ws_size,
                              hipStream_t stream) {
  const float* x = (const float*)d_in[0];
  const float* Wih0 = (const float*)d_in[1];
  const float* Whh0 = (const float*)d_in[2];
  const float* bih0 = (const float*)d_in[3];
  const float* bhh0 = (const float*)d_in[4];
  const float* Wih1 = (const float*)d_in[5];
  const float* Whh1 = (const float*)d_in[6];
  const float* bih1 = (const float*)d_in[7];
  const float* bhh1 = (const float*)d_in[8];
  float* out = (float*)d_out;
  float* xg = (float*)d_ws;  // needs B*T*4H*4 = 33.5 MB of workspace

  xg_gemm<<<dim3((BB * TT) / 64), dim3(256), 0, stream>>>(x, Wih0, bih0, bhh0, xg);
  lstm_scan<<<dim3(BB), dim3(256), 0, stream>>>(xg, Whh0, Wih1, Whh1, bih1, bhh1, out);
}

// Round 3
// 637.032 us; speedup vs baseline: 1.1411x; 1.1411x over previous
//
#include <hip/hip_runtime.h>
#include <stdint.h>

// 2-layer LSTM, B=64, T=1024, D=512, H=32, fp32 in/out.
// Phase 1: xg0 = x @ Wih0^T + b0  (fp32 tiled GEMM, parallel over 65536 rows)
// Phase 2: fused 2-layer scan: ONE WAVE per batch element, zero barriers,
//          zero LDS. Gate dots via v_dot2_f32_f16 (f16 weights in VGPRs,
//          packed-f16 h-state broadcast to SGPRs via v_readlane).

#define TT 1024
#define BB 64
#define DD 512
#define HH 32
#define GG 128  // 4*H

typedef _Float16 h2v __attribute__((ext_vector_type(2)));
typedef __fp16 pk2 __attribute__((ext_vector_type(2)));

__device__ __forceinline__ uint32_t pack2(float lo, float hi) {
  pk2 p = __builtin_amdgcn_cvt_pkrtz(lo, hi);
  return __builtin_bit_cast(uint32_t, p);
}
__device__ __forceinline__ float dot2(uint32_t a, uint32_t b, float acc) {
  return __builtin_amdgcn_fdot2(__builtin_bit_cast(h2v, a),
                                __builtin_bit_cast(h2v, b), acc, false);
}
__device__ __forceinline__ float fast_rcp(float x) { return __builtin_amdgcn_rcpf(x); }
__device__ __forceinline__ float sigm(float s) { return fast_rcp(1.f + __expf(-s)); }
__device__ __forceinline__ float fast_tanh(float x) {
  return fmaf(2.f, fast_rcp(1.f + __expf(-2.f * x)), -1.f);
}
// sigmoid(s) if !ist, tanh(s)=2*sigmoid(2s)-1 if ist (branchless)
__device__ __forceinline__ float act_sel(float s, bool ist) {
  float z = ist ? s + s : s;
  float r = fast_rcp(1.f + __expf(-z));
  return ist ? fmaf(2.f, r, -1.f) : r;
}

// ---------------- Phase 1: xg GEMM (unchanged, passed round 1) ----------------
__global__ __launch_bounds__(256) void xg_gemm(const float* __restrict__ x,
                                               const float* __restrict__ W,
                                               const float* __restrict__ bih,
                                               const float* __restrict__ bhh,
                                               float* __restrict__ outp) {
  __shared__ float xs[16][68];
  __shared__ float ws[16][128];
  const int tid = threadIdx.x;
  const int m0 = blockIdx.x * 64;
  const int tr = tid >> 5;
  const int tc = tid & 31;
  const int tm = tr * 8;
  const int tn = tc * 4;
  const int sxm = tid >> 2;
  const int sxk = (tid & 3) * 4;
  const int swg = tid >> 1;
  const int swk = (tid & 1) * 8;

  float acc[8][4];
#pragma unroll
  for (int i = 0; i < 8; ++i)
#pragma unroll
    for (int j = 0; j < 4; ++j) acc[i][j] = 0.f;

  for (int k0 = 0; k0 < DD; k0 += 16) {
    const float4 xv = *(const float4*)(x + (size_t)(m0 + sxm) * DD + k0 + sxk);
    xs[sxk + 0][sxm] = xv.x;
    xs[sxk + 1][sxm] = xv.y;
    xs[sxk + 2][sxm] = xv.z;
    xs[sxk + 3][sxm] = xv.w;
    const float4 wv0 = *(const float4*)(W + (size_t)swg * DD + k0 + swk);
    const float4 wv1 = *(const float4*)(W + (size_t)swg * DD + k0 + swk + 4);
    ws[swk + 0][swg] = wv0.x;
    ws[swk + 1][swg] = wv0.y;
    ws[swk + 2][swg] = wv0.z;
    ws[swk + 3][swg] = wv0.w;
    ws[swk + 4][swg] = wv1.x;
    ws[swk + 5][swg] = wv1.y;
    ws[swk + 6][swg] = wv1.z;
    ws[swk + 7][swg] = wv1.w;
    __syncthreads();
#pragma unroll
    for (int k = 0; k < 16; ++k) {
      const float4 a0 = *(const float4*)&xs[k][tm];
      const float4 a1 = *(const float4*)&xs[k][tm + 4];
      const float4 wv = *(const float4*)&ws[k][tn];
      const float xr[8] = {a0.x, a0.y, a0.z, a0.w, a1.x, a1.y, a1.z, a1.w};
      const float wr[4] = {wv.x, wv.y, wv.z, wv.w};
#pragma unroll
      for (int i = 0; i < 8; ++i)
#pragma unroll
        for (int j = 0; j < 4; ++j) acc[i][j] = fmaf(xr[i], wr[j], acc[i][j]);
    }
    __syncthreads();
  }
  const float4 bi = *(const float4*)(bih + tn);
  const float4 bh = *(const float4*)(bhh + tn);
  const float bs[4] = {bi.x + bh.x, bi.y + bh.y, bi.z + bh.z, bi.w + bh.w};
#pragma unroll
  for (int i = 0; i < 8; ++i) {
    float4 o;
    o.x = acc[i][0] + bs[0];
    o.y = acc[i][1] + bs[1];
    o.z = acc[i][2] + bs[2];
    o.w = acc[i][3] + bs[3];
    *(float4*)(outp + (size_t)(m0 + tm + i) * GG + tn) = o;
  }
}

// ---------------- Phase 2: single-wave-per-batch scan ----------------
// Lane l (0..63): j = l&31, hi = l>>5.
//  gA = j + 64*hi  (hi=0: i-gate j;  hi=1: g-gate j)
//  gB = gA + 32    (hi=0: f-gate j;  hi=1: o-gate j)
// Combine for j: lanes j and j+32 exchange acts via shfl_xor(32); both halves
// redundantly hold c[j], h[j]. h broadcast: pack f16 pairs, 16x v_readlane.
// Layer1 lags layer0 by 1 step: at iter t, l0 computes h0[t], l1 computes
// h1[t-1]; both dot phases consume h0p=h0[t-1], h1p=h1[t-2] (SGPR state).
__global__ __launch_bounds__(64, 1) void lstm_scan(const float* __restrict__ xg,
                                                   const float* __restrict__ Whh0,
                                                   const float* __restrict__ Wih1,
                                                   const float* __restrict__ Whh1,
                                                   const float* __restrict__ bih1,
                                                   const float* __restrict__ bhh1,
                                                   float* __restrict__ out) {
  const int l = threadIdx.x;
  const int j = l & 31;
  const int hi = l >> 5;
  const int b = blockIdx.x;
  const int gA = j + 64 * hi;
  const int gB = gA + 32;

  // ---- pack weights to f16 pairs (VGPR-resident, constant-indexed) ----
  uint32_t w0A[16], w0B[16], wiA[16], whA[16], wiB[16], whB[16];
#pragma unroll
  for (int q = 0; q < 8; ++q) {
    float4 a = *(const float4*)(Whh0 + (size_t)gA * HH + q * 4);
    float4 c = *(const float4*)(Whh0 + (size_t)gB * HH + q * 4);
    w0A[2 * q] = pack2(a.x, a.y); w0A[2 * q + 1] = pack2(a.z, a.w);
    w0B[2 * q] = pack2(c.x, c.y); w0B[2 * q + 1] = pack2(c.z, c.w);
    float4 d = *(const float4*)(Wih1 + (size_t)gA * HH + q * 4);
    float4 e = *(const float4*)(Wih1 + (size_t)gB * HH + q * 4);
    wiA[2 * q] = pack2(d.x, d.y); wiA[2 * q + 1] = pack2(d.z, d.w);
    wiB[2 * q] = pack2(e.x, e.y); wiB[2 * q + 1] = pack2(e.z, e.w);
    float4 f = *(const float4*)(Whh1 + (size_t)gA * HH + q * 4);
    float4 g = *(const float4*)(Whh1 + (size_t)gB * HH + q * 4);
    whA[2 * q] = pack2(f.x, f.y); whA[2 * q + 1] = pack2(f.z, f.w);
    whB[2 * q] = pack2(g.x, g.y); whB[2 * q + 1] = pack2(g.z, g.w);
  }
  const float b1A = bih1[gA] + bhh1[gA];
  const float b1B = bih1[gB] + bhh1[gB];

  uint32_t h0p[16], h1p[16];  // wave-uniform packed-f16 h state (SGPRs)
#pragma unroll
  for (int k = 0; k < 16; ++k) { h0p[k] = 0u; h1p[k] = 0u; }
  float c0 = 0.f, c1 = 0.f;

  const float* xgp = xg + (size_t)b * TT * GG;
  float* outp = out + (size_t)b * TT * HH;

  // xg prefetch ring, depth 4 (2 dword loads/lane/step)
  float xA[4], xB[4];
#pragma unroll
  for (int u = 0; u < 4; ++u) {
    xA[u] = xgp[u * GG + gA];
    xB[u] = xgp[u * GG + gB];
  }

  for (int tb = 0; tb < TT; tb += 4) {
#pragma unroll
    for (int u = 0; u < 4; ++u) {
      const int t = tb + u;
      float sA0 = xA[u], sB0 = xB[u];
      if (t + 4 < TT) {
        xA[u] = xgp[(size_t)(t + 4) * GG + gA];
        xB[u] = xgp[(size_t)(t + 4) * GG + gB];
      }
      // ---- layer0 dots (uses h0p = h0[t-1]) ----
      float pA = 0.f, pB = 0.f;
#pragma unroll
      for (int k = 0; k < 16; k += 2) {
        sA0 = dot2(w0A[k], h0p[k], sA0);
        pA  = dot2(w0A[k + 1], h0p[k + 1], pA);
        sB0 = dot2(w0B[k], h0p[k], sB0);
        pB  = dot2(w0B[k + 1], h0p[k + 1], pB);
      }
      sA0 += pA; sB0 += pB;
      // ---- layer1 dots for step t-1 (uses h0p=h0[t-1], h1p=h1[t-2]) ----
      float sA1 = b1A, sB1 = b1B, qA = 0.f, qB = 0.f;
#pragma unroll
      for (int k = 0; k < 16; k += 2) {
        sA1 = dot2(wiA[k], h0p[k], sA1);
        qA  = dot2(wiA[k + 1], h0p[k + 1], qA);
        sB1 = dot2(wiB[k], h0p[k], sB1);
        qB  = dot2(wiB[k + 1], h0p[k + 1], qB);
        sA1 = dot2(whA[k], h1p[k], sA1);
        qA  = dot2(whA[k + 1], h1p[k + 1], qA);
        sB1 = dot2(whB[k], h1p[k], sB1);
        qB  = dot2(whB[k + 1], h1p[k + 1], qB);
      }
      sA1 += qA; sB1 += qB;
      // ---- layer0 combine -> h0[t] ----
      {
        float aA = act_sel(sA0, hi != 0);  // i (hi=0) / g (hi=1)
        float aB = sigm(sB0);              // f (hi=0) / o (hi=1)
        float oA = __shfl_xor(aA, 32, 64);
        float oB = __shfl_xor(aB, 32, 64);
        float gi = hi ? oA : aA;
        float gf = hi ? oB : aB;
        float gg = hi ? aA : oA;
        float go = hi ? aB : oB;
        c0 = fmaf(gf, c0, gi * gg);
        float h = go * fast_tanh(c0);
        float oth = __shfl_xor(h, 1, 64);
        float lo = (j & 1) ? oth : h;
        float hh = (j & 1) ? h : oth;
        uint32_t pk = pack2(lo, hh);
#pragma unroll
        for (int m = 0; m < 16; ++m)
          h0p[m] = (uint32_t)__builtin_amdgcn_readlane((int)pk, 2 * m);
      }
      // ---- layer1 combine for step t-1 ----
      if (t > 0) {
        float aA = act_sel(sA1, hi != 0);
        float aB = sigm(sB1);
        float oA = __shfl_xor(aA, 32, 64);
        float oB = __shfl_xor(aB, 32, 64);
        float gi = hi ? oA : aA;
        float gf = hi ? oB : aB;
        float gg = hi ? aA : oA;
        float go = hi ? aB : oB;
        c1 = fmaf(gf, c1, gi * gg);
        float h = go * fast_tanh(c1);
        if (!hi) outp[(size_t)(t - 1) * HH + j] = h;
        float oth = __shfl_xor(h, 1, 64);
        float lo = (j & 1) ? oth : h;
        float hh = (j & 1) ? h : oth;
        uint32_t pk = pack2(lo, hh);
#pragma unroll
        for (int m = 0; m < 16; ++m)
          h1p[m] = (uint32_t)__builtin_amdgcn_readlane((int)pk, 2 * m);
      }
    }
  }
  // ---- final layer1 step (t = TT-1): h0p=h0[TT-1], h1p=h1[TT-2] ----
  {
    float sA1 = b1A, sB1 = b1B, qA = 0.f, qB = 0.f;
#pragma unroll
    for (int k = 0; k < 16; k += 2) {
      sA1 = dot2(wiA[k], h0p[k], sA1);
      qA  = dot2(wiA[k + 1], h0p[k + 1], qA);
      sB1 = dot2(wiB[k], h0p[k], sB1);
      qB  = dot2(wiB[k + 1], h0p[k + 1], qB);
      sA1 = dot2(whA[k], h1p[k], sA1);
      qA  = dot2(whA[k + 1], h1p[k + 1], qA);
      sB1 = dot2(whB[k], h1p[k], sB1);
      qB  = dot2(whB[k + 1], h1p[k + 1], qB);
    }
    sA1 += qA; sB1 += qB;
    float aA = act_sel(sA1, hi != 0);
    float aB = sigm(sB1);
    float oA = __shfl_xor(aA, 32, 64);
    float oB = __shfl_xor(aB, 32, 64);
    float gi = hi ? oA : aA;
    float gf = hi ? oB : aB;
    float gg = hi ? aA : oA;
    float go = hi ? aB : oB;
    c1 = fmaf(gf, c1, gi * gg);
    float h = go * fast_tanh(c1);
    if (!hi) outp[(size_t)(TT - 1) * HH + j] = h;
  }
}

extern "C" void kernel_launch(void* const* d_in, const int* in_sizes, int n_in,
                              void* d_out, int out_size, void* d_ws, size_t ws_size,
                              hipStream_t stream) {
  const float* x = (const float*)d_in[0];
  const float* Wih0 = (const float*)d_in[1];
  const float* Whh0 = (const float*)d_in[2];
  const float* bih0 = (const float*)d_in[3];
  const float* bhh0 = (const float*)d_in[4];
  const float* Wih1 = (const float*)d_in[5];
  const float* Whh1 = (const float*)d_in[6];
  const float* bih1 = (const float*)d_in[7];
  const float* bhh1 = (const float*)d_in[8];
  float* out = (float*)d_out;
  float* xg = (float*)d_ws;  // B*T*4H*4 = 33.5 MB scratch

  xg_gemm<<<dim3((BB * TT) / 64), dim3(256), 0, stream>>>(x, Wih0, bih0, bhh0, xg);
  lstm_scan<<<dim3(BB), dim3(64), 0, stream>>>(xg, Whh0, Wih1, Whh1, bih1, bhh1, out);
}

// Round 6
// 571.524 us; speedup vs baseline: 1.2718x; 1.1146x over previous
//
#include <hip/hip_runtime.h>
#include <stdint.h>

// 2-layer LSTM, B=64, T=1024, D=512, H=32, fp32 in/out.
// Phase 1: xg0 = x @ Wih0^T + b0  (fp32 tiled GEMM, parallel over 65536 rows)
// Phase 2: fused 2-layer scan: ONE WAVE per batch element, zero barriers,
//          zero LDS, zero DS-pipe shuffles. Gate dots via v_dot2_f32_f16;
//          xor-32 gate exchange via v_permlane32_swap_b32 (VALU) with
//          order-proof XOR partner extraction; pair-pack via DPP quad_perm;
//          h broadcast via v_readlane -> wave-uniform SGPRs.

#define TT 1024
#define BB 64
#define DD 512
#define HH 32
#define GG 128  // 4*H

typedef _Float16 h2v __attribute__((ext_vector_type(2)));
typedef __fp16 pk2 __attribute__((ext_vector_type(2)));
typedef int int2v __attribute__((ext_vector_type(2)));

__device__ __forceinline__ uint32_t pack2(float lo, float hi) {
  pk2 p = __builtin_amdgcn_cvt_pkrtz(lo, hi);
  return __builtin_bit_cast(uint32_t, p);
}
__device__ __forceinline__ float dot2(uint32_t a, uint32_t b, float acc) {
  return __builtin_amdgcn_fdot2(__builtin_bit_cast(h2v, a),
                                __builtin_bit_cast(h2v, b), acc, false);
}
__device__ __forceinline__ float fast_rcp(float x) { return __builtin_amdgcn_rcpf(x); }
__device__ __forceinline__ float sigm(float s) { return fast_rcp(1.f + __expf(-s)); }
__device__ __forceinline__ float fast_tanh(float x) {
  return fmaf(2.f, fast_rcp(1.f + __expf(-2.f * x)), -1.f);
}
// sigmoid(s) if !ist, tanh(s)=2*sigmoid(2s)-1 if ist (branchless)
__device__ __forceinline__ float act_sel(float s, bool ist) {
  float z = ist ? s + s : s;
  float r = fast_rcp(1.f + __expf(-z));
  return ist ? fmaf(2.f, r, -1.f) : r;
}

// xor-32 partner, pure VALU. v_permlane32_swap_b32 leaves each lane holding
// {self, partner} across the two result words (order depends on operand
// convention); partner = r.x ^ r.y ^ self is exact under either order.
__device__ __forceinline__ float partner32(float x) {
  int xi = __builtin_bit_cast(int, x);
#if __has_builtin(__builtin_amdgcn_permlane32_swap)
  int2v r = __builtin_amdgcn_permlane32_swap(xi, xi, false, false);
  return __builtin_bit_cast(float, r.x ^ r.y ^ xi);
#else
  int a = xi, b = xi;
  asm("v_permlane32_swap_b32 %0, %1" : "+v"(a), "+v"(b));
  return __builtin_bit_cast(float, a ^ b ^ xi);
#endif
}

// xor-1 neighbor exchange via DPP quad_perm [1,0,3,2] (VALU-speed)
__device__ __forceinline__ float xor1_dpp(float x) {
  int xi = __builtin_bit_cast(int, x);
  int r = __builtin_amdgcn_update_dpp(xi, xi, 0xB1, 0xF, 0xF, true);
  return __builtin_bit_cast(float, r);
}

// ---------------- Phase 1: xg GEMM (unchanged, passed round 1) ----------------
__global__ __launch_bounds__(256) void xg_gemm(const float* __restrict__ x,
                                               const float* __restrict__ W,
                                               const float* __restrict__ bih,
                                               const float* __restrict__ bhh,
                                               float* __restrict__ outp) {
  __shared__ float xs[16][68];
  __shared__ float ws[16][128];
  const int tid = threadIdx.x;
  const int m0 = blockIdx.x * 64;
  const int tr = tid >> 5;
  const int tc = tid & 31;
  const int tm = tr * 8;
  const int tn = tc * 4;
  const int sxm = tid >> 2;
  const int sxk = (tid & 3) * 4;
  const int swg = tid >> 1;
  const int swk = (tid & 1) * 8;

  float acc[8][4];
#pragma unroll
  for (int i = 0; i < 8; ++i)
#pragma unroll
    for (int j = 0; j < 4; ++j) acc[i][j] = 0.f;

  for (int k0 = 0; k0 < DD; k0 += 16) {
    const float4 xv = *(const float4*)(x + (size_t)(m0 + sxm) * DD + k0 + sxk);
    xs[sxk + 0][sxm] = xv.x;
    xs[sxk + 1][sxm] = xv.y;
    xs[sxk + 2][sxm] = xv.z;
    xs[sxk + 3][sxm] = xv.w;
    const float4 wv0 = *(const float4*)(W + (size_t)swg * DD + k0 + swk);
    const float4 wv1 = *(const float4*)(W + (size_t)swg * DD + k0 + swk + 4);
    ws[swk + 0][swg] = wv0.x;
    ws[swk + 1][swg] = wv0.y;
    ws[swk + 2][swg] = wv0.z;
    ws[swk + 3][swg] = wv0.w;
    ws[swk + 4][swg] = wv1.x;
    ws[swk + 5][swg] = wv1.y;
    ws[swk + 6][swg] = wv1.z;
    ws[swk + 7][swg] = wv1.w;
    __syncthreads();
#pragma unroll
    for (int k = 0; k < 16; ++k) {
      const float4 a0 = *(const float4*)&xs[k][tm];
      const float4 a1 = *(const float4*)&xs[k][tm + 4];
      const float4 wv = *(const float4*)&ws[k][tn];
      const float xr[8] = {a0.x, a0.y, a0.z, a0.w, a1.x, a1.y, a1.z, a1.w};
      const float wr[4] = {wv.x, wv.y, wv.z, wv.w};
#pragma unroll
      for (int i = 0; i < 8; ++i)
#pragma unroll
        for (int j = 0; j < 4; ++j) acc[i][j] = fmaf(xr[i], wr[j], acc[i][j]);
    }
    __syncthreads();
  }
  const float4 bi = *(const float4*)(bih + tn);
  const float4 bh = *(const float4*)(bhh + tn);
  const float bs[4] = {bi.x + bh.x, bi.y + bh.y, bi.z + bh.z, bi.w + bh.w};
#pragma unroll
  for (int i = 0; i < 8; ++i) {
    float4 o;
    o.x = acc[i][0] + bs[0];
    o.y = acc[i][1] + bs[1];
    o.z = acc[i][2] + bs[2];
    o.w = acc[i][3] + bs[3];
    *(float4*)(outp + (size_t)(m0 + tm + i) * GG + tn) = o;
  }
}

// ---------------- Phase 2: single-wave-per-batch scan ----------------
// Lane l (0..63): j = l&31, hi = l>>5.
//  gA = j + 64*hi  (hi=0: i-gate j;  hi=1: g-gate j)
//  gB = gA + 32    (hi=0: f-gate j;  hi=1: o-gate j)
// Combine: lanes j / j+32 exchange acts via partner32 (VALU permlane swap);
// both halves redundantly hold c[j], h[j]. h broadcast: DPP xor1 pair-pack
// to f16, then 16x v_readlane into wave-uniform SGPRs.
// Layer1 lags layer0 by 1 step.
__global__ __launch_bounds__(64, 1) void lstm_scan(const float* __restrict__ xg,
                                                   const float* __restrict__ Whh0,
                                                   const float* __restrict__ Wih1,
                                                   const float* __restrict__ Whh1,
                                                   const float* __restrict__ bih1,
                                                   const float* __restrict__ bhh1,
                                                   float* __restrict__ out) {
  const int l = threadIdx.x;
  const int j = l & 31;
  const int hi = l >> 5;
  const int b = blockIdx.x;
  const int gA = j + 64 * hi;
  const int gB = gA + 32;

  // ---- pack weights to f16 pairs (VGPR-resident, constant-indexed) ----
  uint32_t w0A[16], w0B[16], wiA[16], whA[16], wiB[16], whB[16];
#pragma unroll
  for (int q = 0; q < 8; ++q) {
    float4 a = *(const float4*)(Whh0 + (size_t)gA * HH + q * 4);
    float4 c = *(const float4*)(Whh0 + (size_t)gB * HH + q * 4);
    w0A[2 * q] = pack2(a.x, a.y); w0A[2 * q + 1] = pack2(a.z, a.w);
    w0B[2 * q] = pack2(c.x, c.y); w0B[2 * q + 1] = pack2(c.z, c.w);
    float4 d = *(const float4*)(Wih1 + (size_t)gA * HH + q * 4);
    float4 e = *(const float4*)(Wih1 + (size_t)gB * HH + q * 4);
    wiA[2 * q] = pack2(d.x, d.y); wiA[2 * q + 1] = pack2(d.z, d.w);
    wiB[2 * q] = pack2(e.x, e.y); wiB[2 * q + 1] = pack2(e.z, e.w);
    float4 f = *(const float4*)(Whh1 + (size_t)gA * HH + q * 4);
    float4 g = *(const float4*)(Whh1 + (size_t)gB * HH + q * 4);
    whA[2 * q] = pack2(f.x, f.y); whA[2 * q + 1] = pack2(f.z, f.w);
    whB[2 * q] = pack2(g.x, g.y); whB[2 * q + 1] = pack2(g.z, g.w);
  }
  const float b1A = bih1[gA] + bhh1[gA];
  const float b1B = bih1[gB] + bhh1[gB];

  uint32_t h0p[16], h1p[16];  // wave-uniform packed-f16 h state (SGPRs)
#pragma unroll
  for (int k = 0; k < 16; ++k) { h0p[k] = 0u; h1p[k] = 0u; }
  float c0 = 0.f, c1 = 0.f;

  const float* xgp = xg + (size_t)b * TT * GG;
  float* outp = out + (size_t)b * TT * HH;

  // xg prefetch ring, depth 4 (2 dword loads/lane/step)
  float xA[4], xB[4];
#pragma unroll
  for (int u = 0; u < 4; ++u) {
    xA[u] = xgp[u * GG + gA];
    xB[u] = xgp[u * GG + gB];
  }

  for (int tb = 0; tb < TT; tb += 4) {
#pragma unroll
    for (int u = 0; u < 4; ++u) {
      const int t = tb + u;
      float sA0 = xA[u], sB0 = xB[u];
      const int tp = (t + 4 < TT) ? (t + 4) : (TT - 1);
      xA[u] = xgp[(size_t)tp * GG + gA];
      xB[u] = xgp[(size_t)tp * GG + gB];
      // ---- layer0 dots (uses h0p = h0[t-1]) ----
      float pA = 0.f, pB = 0.f;
#pragma unroll
      for (int k = 0; k < 16; k += 2) {
        sA0 = dot2(w0A[k], h0p[k], sA0);
        pA  = dot2(w0A[k + 1], h0p[k + 1], pA);
        sB0 = dot2(w0B[k], h0p[k], sB0);
        pB  = dot2(w0B[k + 1], h0p[k + 1], pB);
      }
      sA0 += pA; sB0 += pB;
      // ---- layer1 dots for step t-1 (uses h0p=h0[t-1], h1p=h1[t-2]) ----
      float sA1 = b1A, sB1 = b1B, qA = 0.f, qB = 0.f;
#pragma unroll
      for (int k = 0; k < 16; k += 2) {
        sA1 = dot2(wiA[k], h0p[k], sA1);
        qA  = dot2(wiA[k + 1], h0p[k + 1], qA);
        sB1 = dot2(wiB[k], h0p[k], sB1);
        qB  = dot2(wiB[k + 1], h0p[k + 1], qB);
        sA1 = dot2(whA[k], h1p[k], sA1);
        qA  = dot2(whA[k + 1], h1p[k + 1], qA);
        sB1 = dot2(whB[k], h1p[k], sB1);
        qB  = dot2(whB[k + 1], h1p[k + 1], qB);
      }
      sA1 += qA; sB1 += qB;
      // ---- layer0 combine -> h0[t] ----
      {
        float aA = act_sel(sA0, hi != 0);  // i (hi=0) / g (hi=1)
        float aB = sigm(sB0);              // f (hi=0) / o (hi=1)
        float pAx = partner32(aA);
        float pBx = partner32(aB);
        float gi = hi ? pAx : aA;
        float gf = hi ? pBx : aB;
        float gg = hi ? aA : pAx;
        float go = hi ? aB : pBx;
        c0 = fmaf(gf, c0, gi * gg);
        float h = go * fast_tanh(c0);
        float oth = xor1_dpp(h);
        float lo = (j & 1) ? oth : h;
        float hh = (j & 1) ? h : oth;
        uint32_t pk = pack2(lo, hh);
#pragma unroll
        for (int m = 0; m < 16; ++m)
          h0p[m] = (uint32_t)__builtin_amdgcn_readlane((int)pk, 2 * m);
      }
      // ---- layer1 combine for step t-1 ----
      if (t > 0) {
        float aA = act_sel(sA1, hi != 0);
        float aB = sigm(sB1);
        float pAx = partner32(aA);
        float pBx = partner32(aB);
        float gi = hi ? pAx : aA;
        float gf = hi ? pBx : aB;
        float gg = hi ? aA : pAx;
        float go = hi ? aB : pBx;
        c1 = fmaf(gf, c1, gi * gg);
        float h = go * fast_tanh(c1);
        if (!hi) outp[(size_t)(t - 1) * HH + j] = h;
        float oth = xor1_dpp(h);
        float lo = (j & 1) ? oth : h;
        float hh = (j & 1) ? h : oth;
        uint32_t pk = pack2(lo, hh);
#pragma unroll
        for (int m = 0; m < 16; ++m)
          h1p[m] = (uint32_t)__builtin_amdgcn_readlane((int)pk, 2 * m);
      }
    }
  }
  // ---- final layer1 step (t = TT-1): h0p=h0[TT-1], h1p=h1[TT-2] ----
  {
    float sA1 = b1A, sB1 = b1B, qA = 0.f, qB = 0.f;
#pragma unroll
    for (int k = 0; k < 16; k += 2) {
      sA1 = dot2(wiA[k], h0p[k], sA1);
      qA  = dot2(wiA[k + 1], h0p[k + 1], qA);
      sB1 = dot2(wiB[k], h0p[k], sB1);
      qB  = dot2(wiB[k + 1], h0p[k + 1], qB);
      sA1 = dot2(whA[k], h1p[k], sA1);
      qA  = dot2(whA[k + 1], h1p[k + 1], qA);
      sB1 = dot2(whB[k], h1p[k], sB1);
      qB  = dot2(whB[k + 1], h1p[k + 1], qB);
    }
    sA1 += qA; sB1 += qB;
    float aA = act_sel(sA1, hi != 0);
    float aB = sigm(sB1);
    float pAx = partner32(aA);
    float pBx = partner32(aB);
    float gi = hi ? pAx : aA;
    float gf = hi ? pBx : aB;
    float gg = hi ? aA : pAx;
    float go = hi ? aB : pBx;
    c1 = fmaf(gf, c1, gi * gg);
    float h = go * fast_tanh(c1);
    if (!hi) outp[(size_t)(TT - 1) * HH + j] = h;
  }
}

extern "C" void kernel_launch(void* const* d_in, const int* in_sizes, int n_in,
                              void* d_out, int out_size, void* d_ws, size_t ws_size,
                              hipStream_t stream) {
  const float* x = (const float*)d_in[0];
  const float* Wih0 = (const float*)d_in[1];
  const float* Whh0 = (const float*)d_in[2];
  const float* bih0 = (const float*)d_in[3];
  const float* bhh0 = (const float*)d_in[4];
  const float* Wih1 = (const float*)d_in[5];
  const float* Whh1 = (const float*)d_in[6];
  const float* bih1 = (const float*)d_in[7];
  const float* bhh1 = (const float*)d_in[8];
  float* out = (float*)d_out;
  float* xg = (float*)d_ws;  // B*T*4H*4 = 33.5 MB scratch

  xg_gemm<<<dim3((BB * TT) / 64), dim3(256), 0, stream>>>(x, Wih0, bih0, bhh0, xg);
  lstm_scan<<<dim3(BB), dim3(64), 0, stream>>>(xg, Whh0, Wih1, Whh1, bih1, bhh1, out);
}